// Round 10
// baseline (475.304 us; speedup 1.0000x reference)
//
#include <hip/hip_runtime.h>

#define N_NODES 50000
#define N_EDGES 800000
#define N_LABEL 200000
#define HID 64
#define SCAN_BLOCKS 196   // ceil(50000/256)
#define NBUCKET 1563      // ceil(50000/32), bucket = dst >> 5

// ---------------- ws layout (4-byte units) ----------------
static const size_t OFF_W1C  = 0;                                   // 64*64
static const size_t OFF_B1C  = 4096;                                // 64
static const size_t OFF_CE   = 4160;                                // 2
static const size_t OFF_H    = 4224;                                // 50000*64 (also aliases int4 tmp[800000] during CSR build)
static const size_t OFF_AGG  = OFF_H    + (size_t)N_NODES * HID;    // 50000*64
static const size_t OFF_ASRC = OFF_AGG  + (size_t)N_NODES * HID;    // 50000
static const size_t OFF_ADST = OFF_ASRC + (size_t)N_NODES;          // 50000
static const size_t OFF_ROW  = OFF_ADST + (size_t)N_NODES;          // 50002 (int, padded)
static const size_t OFF_CNT  = OFF_ROW  + (size_t)N_NODES + 2;      // 50000 (int)
static const size_t OFF_PACK = OFF_CNT  + (size_t)N_NODES;          // 2*800000 (int2), 8B-aligned
static const size_t OFF_BSUM = OFF_PACK + 2 * (size_t)N_EDGES;      // 256 (int)
static const size_t OFF_BB   = OFF_BSUM + 256;                      // 1563 (int) bucket bases
static const size_t OFF_BT   = OFF_BB   + NBUCKET;                  // 1563 (int) bucket tickets
// total ~= 33 MB  (tmp aliases H: 800000*int4 = 12.8MB == H's 12.8MB)

// Fold author linear into GAT1 weight; compute per-edge-attr scalar coefs.
__global__ void prep_kernel(const float* __restrict__ Wa, const float* __restrict__ ba,
                            const float* __restrict__ c1W,
                            const float* __restrict__ c1We, const float* __restrict__ c1ae,
                            const float* __restrict__ c2We, const float* __restrict__ c2ae,
                            float* __restrict__ W1c, float* __restrict__ b1c,
                            float* __restrict__ ce) {
    int t = threadIdx.x;
    for (int idx = t; idx < 64 * 64; idx += 256) {
        int i = idx >> 6, j = idx & 63;
        float s = 0.f;
        for (int k = 0; k < 64; ++k) s += Wa[i * 64 + k] * c1W[k * 64 + j];
        W1c[idx] = s;
    }
    if (t < 64) {
        float s = 0.f;
        for (int k = 0; k < 64; ++k) s += ba[k] * c1W[k * 64 + t];
        b1c[t] = s;
    }
    if (t == 64) {
        float s = 0.f;
        for (int k = 0; k < 64; ++k) s += c1We[k] * c1ae[k];
        ce[0] = s;
    }
    if (t == 65) {
        float s = 0.f;
        for (int k = 0; k < 64; ++k) s += c2We[k] * c2ae[k];
        ce[1] = s;
    }
}

// ---------------- CSR build ----------------
__global__ void hist_kernel(const int* __restrict__ ei, int* __restrict__ cnt) {
    int e = blockIdx.x * blockDim.x + threadIdx.x;
    if (e < N_EDGES) atomicAdd(&cnt[ei[N_EDGES + e]], 1);
}

// Parallel scan, phase A: per-block (256-wide) sums.
__global__ void block_sum_kernel(const int* __restrict__ cnt, int* __restrict__ bsum) {
    __shared__ int red[256];
    int t = threadIdx.x;
    int i = blockIdx.x * 256 + t;
    red[t] = (i < N_NODES) ? cnt[i] : 0;
    __syncthreads();
    for (int off = 128; off > 0; off >>= 1) {
        if (t < off) red[t] += red[t + off];
        __syncthreads();
    }
    if (t == 0) bsum[blockIdx.x] = red[0];
}

// Phase B: one block scans the 196 block sums -> exclusive bases (in place).
__global__ void scan_bsum_kernel(int* __restrict__ bsum) {
    __shared__ int s[256];
    int t = threadIdx.x;
    int v = (t < SCAN_BLOCKS) ? bsum[t] : 0;
    s[t] = v;
    __syncthreads();
    for (int off = 1; off < 256; off <<= 1) {
        int u = (t >= off) ? s[t - off] : 0;
        __syncthreads();
        s[t] += u;
        __syncthreads();
    }
    if (t < SCAN_BLOCKS) bsum[t] = s[t] - v;   // exclusive base
}

// Phase C: per-block inclusive scan + base -> exclusive row_ptr.
__global__ void scan_final_kernel(const int* __restrict__ cnt,
                                  const int* __restrict__ bsum,
                                  int* __restrict__ row_ptr) {
    __shared__ int s[256];
    int t = threadIdx.x;
    int i = blockIdx.x * 256 + t;
    int v = (i < N_NODES) ? cnt[i] : 0;
    s[t] = v;
    __syncthreads();
    for (int off = 1; off < 256; off <<= 1) {
        int u = (t >= off) ? s[t - off] : 0;
        __syncthreads();
        s[t] += u;
        __syncthreads();
    }
    int excl = s[t] - v + bsum[blockIdx.x];
    if (i < N_NODES) row_ptr[i] = excl;
    if (i == N_NODES - 1) row_ptr[N_NODES] = excl + v;
}

// Bucket bases from row_ptr (bucket b = nodes [32b, 32b+32)); zero tickets.
__global__ void bbase_kernel(const int* __restrict__ row_ptr,
                             int* __restrict__ bbase, int* __restrict__ btick) {
    int b = blockIdx.x * blockDim.x + threadIdx.x;
    if (b < NBUCKET) {
        int n0 = b * 32;
        bbase[b] = row_ptr[n0 < N_NODES ? n0 : N_NODES];
        btick[b] = 0;
    }
}

// Scatter phase 1: append edge {src,dst,ea} into its bucket's CSR region.
// Writes cluster at 1563 advancing cursors -> ~1x line amplification.
__global__ void bucket_scatter_kernel(const int* __restrict__ ei,
                                      const float* __restrict__ ea,
                                      const int* __restrict__ bbase,
                                      int* __restrict__ btick,
                                      int4* __restrict__ tmp) {
    int e = blockIdx.x * blockDim.x + threadIdx.x;
    if (e >= N_EDGES) return;
    int d = ei[N_EDGES + e];
    int b = d >> 5;
    int pos = bbase[b] + atomicAdd(&btick[b], 1);
    int4 pr; pr.x = ei[e]; pr.y = d; pr.z = __float_as_int(ea[e]); pr.w = 0;
    tmp[pos] = pr;
}

// Scatter phase 2: exact per-node placement. Write window == read window (~4KB)
// -> L2-local, no line amplification. Consumes cnt (ends at zero).
__global__ void final_scatter_kernel(const int4* __restrict__ tmp,
                                     const int* __restrict__ row_ptr,
                                     int* __restrict__ cnt,
                                     int2* __restrict__ pack) {
    int e = blockIdx.x * blockDim.x + threadIdx.x;
    if (e >= N_EDGES) return;
    int4 pr = tmp[e];
    int d = pr.y;
    int old = atomicSub(&cnt[d], 1);           // old in [1..deg]
    int pos = row_ptr[d] + old - 1;
    int2 o; o.x = pr.x; o.y = pr.z;
    pack[pos] = o;
}

// H = X @ W (+postb) ; Asrc = H . avs ; Adst = H . avd
// W column held in 64 VGPRs per lane; X row loaded at wave-uniform addresses.
__global__ void gemm_attn_kernel(const float* __restrict__ X,
                                 const float* __restrict__ W,
                                 const float* __restrict__ postb, int has_postb,
                                 const float* __restrict__ avs,
                                 const float* __restrict__ avd,
                                 float* __restrict__ H,
                                 float* __restrict__ Asrc, float* __restrict__ Adst) {
    int lane = threadIdx.x & 63;
    int wid  = __builtin_amdgcn_readfirstlane(threadIdx.x >> 6);  // uniform
    int gwave  = blockIdx.x * 4 + wid;
    int nwaves = gridDim.x * 4;
    float wcol[64];
#pragma unroll
    for (int k = 0; k < 64; ++k) wcol[k] = W[k * 64 + lane];
    float as_l = avs[lane], ad_l = avd[lane];
    float ob = has_postb ? postb[lane] : 0.f;
    for (int row = gwave; row < N_NODES; row += nwaves) {
        const float4* xr4 = (const float4*)(X + (size_t)row * 64);  // uniform addr
        float acc = ob;
#pragma unroll
        for (int i = 0; i < 16; ++i) {
            float4 xq = xr4[i];
            acc = fmaf(xq.x, wcol[4 * i + 0], acc);
            acc = fmaf(xq.y, wcol[4 * i + 1], acc);
            acc = fmaf(xq.z, wcol[4 * i + 2], acc);
            acc = fmaf(xq.w, wcol[4 * i + 3], acc);
        }
        H[(size_t)row * 64 + lane] = acc;
        float s1 = acc * as_l, s2 = acc * ad_l;
#pragma unroll
        for (int off = 32; off > 0; off >>= 1) {
            s1 += __shfl_xor(s1, off);
            s2 += __shfl_xor(s2, off);
        }
        if (lane == 0) { Asrc[row] = s1; Adst[row] = s2; }
    }
}

// Fused per-dst gather: alpha -> exp -> weighted sum -> normalize (+opt bias/relu).
// One wave per node: lane = 4 edge-subgroups x 16 feature-lanes (float4 each).
__global__ void aggregate_csr_kernel(const int* __restrict__ row_ptr,
                                     const int2* __restrict__ pack,
                                     const float* __restrict__ Asrc,
                                     const float* __restrict__ Adst,
                                     const float* __restrict__ cep,
                                     const float* __restrict__ H,
                                     float* __restrict__ Agg,
                                     const float* __restrict__ obias, int do_relu) {
    int t    = threadIdx.x;
    int q    = t & 15;          // feature quad (16 lanes x float4 = 64 feats)
    int sub  = (t >> 4) & 3;    // edge subgroup 0..3
    int wid  = t >> 6;          // wave in block
    int node = blockIdx.x * 4 + wid;
    if (node >= N_NODES) return;
    float ce = *cep;
    float ad = Adst[node];
    int beg = row_ptr[node], end = row_ptr[node + 1];
    float ax = 0.f, ay = 0.f, az = 0.f, aw = 0.f, accp = 0.f;
    for (int pos = beg + sub; pos < end; pos += 4) {
        int2  pr  = pack[pos];
        int   s   = pr.x;
        float ev  = __int_as_float(pr.y);
        float as_ = Asrc[s];
        float4 hv = *(const float4*)(H + (size_t)s * 64 + q * 4);
        float al = as_ + ad + ev * ce;
        al = al >= 0.f ? al : 0.2f * al;
        float p = __expf(al);
        ax += p * hv.x; ay += p * hv.y; az += p * hv.z; aw += p * hv.w;
        accp += p;
    }
    // reduce across the 4 edge-subgroups (lane = sub*16 + q): xor 16 then 32
    ax += __shfl_xor(ax, 16); ax += __shfl_xor(ax, 32);
    ay += __shfl_xor(ay, 16); ay += __shfl_xor(ay, 32);
    az += __shfl_xor(az, 16); az += __shfl_xor(az, 32);
    aw += __shfl_xor(aw, 16); aw += __shfl_xor(aw, 32);
    accp += __shfl_xor(accp, 16); accp += __shfl_xor(accp, 32);
    if (sub == 0) {
        float inv = 1.f / (accp + 1e-16f);
        float4 o; o.x = ax * inv; o.y = ay * inv; o.z = az * inv; o.w = aw * inv;
        if (obias) {
            float4 b = ((const float4*)obias)[q];
            o.x += b.x; o.y += b.y; o.z += b.z; o.w += b.w;
            if (do_relu) {
                o.x = fmaxf(o.x, 0.f); o.y = fmaxf(o.y, 0.f);
                o.z = fmaxf(o.z, 0.f); o.w = fmaxf(o.w, 0.f);
            }
        }
        *(float4*)(Agg + (size_t)node * 64 + q * 4) = o;
    }
}

// Edge classifier: out[e] = dot(Agg[i]+b, Agg[j]+b). 16-lane group per edge, float4.
__global__ void classify_kernel(const int* __restrict__ eli,
                                const float* __restrict__ Agg,
                                const float* __restrict__ bias,
                                float* __restrict__ out) {
    int t    = threadIdx.x;
    int q    = t & 15;
    int grp  = (blockIdx.x * blockDim.x + t) >> 4;
    if (grp >= N_LABEL) return;
    int e = grp;
    float4 b = ((const float4*)bias)[q];
    int i = eli[e], j = eli[N_LABEL + e];
    float4 a = ((const float4*)(Agg + (size_t)i * 64))[q];
    float4 c = ((const float4*)(Agg + (size_t)j * 64))[q];
    float s = (a.x + b.x) * (c.x + b.x) + (a.y + b.y) * (c.y + b.y) +
              (a.z + b.z) * (c.z + b.z) + (a.w + b.w) * (c.w + b.w);
#pragma unroll
    for (int off = 8; off > 0; off >>= 1) s += __shfl_xor(s, off);
    if (q == 0) out[e] = s;
}

extern "C" void kernel_launch(void* const* d_in, const int* in_sizes, int n_in,
                              void* d_out, int out_size, void* d_ws, size_t ws_size,
                              hipStream_t stream) {
    const float* x    = (const float*)d_in[0];
    const float* ea   = (const float*)d_in[1];
    const float* Wa   = (const float*)d_in[2];
    const float* ba   = (const float*)d_in[3];
    const float* c1W  = (const float*)d_in[4];
    const float* c1as = (const float*)d_in[5];
    const float* c1ad = (const float*)d_in[6];
    const float* c1We = (const float*)d_in[7];
    const float* c1ae = (const float*)d_in[8];
    const float* c1b  = (const float*)d_in[9];
    const float* c2W  = (const float*)d_in[10];
    const float* c2as = (const float*)d_in[11];
    const float* c2ad = (const float*)d_in[12];
    const float* c2We = (const float*)d_in[13];
    const float* c2ae = (const float*)d_in[14];
    const float* c2b  = (const float*)d_in[15];
    const int*   ei   = (const int*)d_in[16];
    const int*   eli  = (const int*)d_in[17];
    float* out = (float*)d_out;

    float* w    = (float*)d_ws;
    float* W1c  = w + OFF_W1C;
    float* b1c  = w + OFF_B1C;
    float* ce   = w + OFF_CE;
    float* H    = w + OFF_H;
    float* Agg  = w + OFF_AGG;
    float* Asrc = w + OFF_ASRC;
    float* Adst = w + OFF_ADST;
    int*   rowp = (int*)(w + OFF_ROW);
    int*   cnt  = (int*)(w + OFF_CNT);
    int2*  pack = (int2*)(w + OFF_PACK);
    int*   bsum = (int*)(w + OFF_BSUM);
    int*   bbas = (int*)(w + OFF_BB);
    int*   btic = (int*)(w + OFF_BT);
    int4*  tmp  = (int4*)(w + OFF_H);   // aliases H: dead until GEMM-1 (stream-ordered)

    // ---- prep + CSR build (structure shared by both layers) ----
    prep_kernel<<<1, 256, 0, stream>>>(Wa, ba, c1W, c1We, c1ae, c2We, c2ae,
                                       W1c, b1c, ce);
    hipMemsetAsync(cnt, 0, (size_t)N_NODES * sizeof(int), stream);
    hist_kernel<<<(N_EDGES + 255) / 256, 256, 0, stream>>>(ei, cnt);
    block_sum_kernel<<<SCAN_BLOCKS, 256, 0, stream>>>(cnt, bsum);
    scan_bsum_kernel<<<1, 256, 0, stream>>>(bsum);
    scan_final_kernel<<<SCAN_BLOCKS, 256, 0, stream>>>(cnt, bsum, rowp);
    bbase_kernel<<<(NBUCKET + 255) / 256, 256, 0, stream>>>(rowp, bbas, btic);
    bucket_scatter_kernel<<<(N_EDGES + 255) / 256, 256, 0, stream>>>(ei, ea, bbas,
                                                                     btic, tmp);
    final_scatter_kernel<<<(N_EDGES + 255) / 256, 256, 0, stream>>>(tmp, rowp,
                                                                    cnt, pack);

    // ---- layer 1: H1 = x @ W1c + b1c ; agg1 = softmax-agg(H1) + c1b, relu ----
    gemm_attn_kernel<<<1024, 256, 0, stream>>>(x, W1c, b1c, 1,
                                               c1as, c1ad, H, Asrc, Adst);
    aggregate_csr_kernel<<<12500, 256, 0, stream>>>(rowp, pack, Asrc, Adst,
                                                    ce + 0, H, Agg, c1b, 1);

    // ---- layer 2: H2 = agg1 @ c2W ; agg2 = softmax-agg(H2) ----
    gemm_attn_kernel<<<1024, 256, 0, stream>>>(Agg, c2W, nullptr, 0,
                                               c2as, c2ad, H, Asrc, Adst);
    aggregate_csr_kernel<<<12500, 256, 0, stream>>>(rowp, pack, Asrc, Adst,
                                                    ce + 1, H, Agg, nullptr, 0);

    // ---- classifier (adds c2b to both operands) ----
    classify_kernel<<<(N_LABEL * 16 + 255) / 256, 256, 0, stream>>>(eli, Agg, c2b, out);
}

// Round 12
// 323.759 us; speedup vs baseline: 1.4681x; 1.4681x over previous
//
#include <hip/hip_runtime.h>

#define N_NODES 50000
#define N_EDGES 800000
#define N_LABEL 200000
#define HID 64
#define SCAN_BLOCKS 196   // ceil(50000/256)
#define NBKT 196          // dst >> 8  (256 nodes per bucket)
#define NBLK 391          // ceil(800000/2048) input blocks of 2048 edges

// ---------------- ws layout (4-byte units) ----------------
static const size_t OFF_W1C  = 0;                                   // 64*64
static const size_t OFF_B1C  = 4096;                                // 64
static const size_t OFF_CE   = 4160;                                // 2
static const size_t OFF_H    = 4224;                                // 50000*64 (aliases int2 tmp[800000] during CSR build)
static const size_t OFF_AGG  = OFF_H    + (size_t)N_NODES * HID;    // 50000*64
static const size_t OFF_ASRC = OFF_AGG  + (size_t)N_NODES * HID;    // 50000
static const size_t OFF_ADST = OFF_ASRC + (size_t)N_NODES;          // 50000
static const size_t OFF_ROW  = OFF_ADST + (size_t)N_NODES;          // 50002 (int, padded)
static const size_t OFF_CNT  = OFF_ROW  + (size_t)N_NODES + 2;      // 50000 (int)
static const size_t OFF_PACK = OFF_CNT  + (size_t)N_NODES;          // 2*800000 (int2), 8B-aligned
static const size_t OFF_BSUM = OFF_PACK + 2 * (size_t)N_EDGES;      // 256 (int)
static const size_t OFF_CM   = OFF_BSUM + 256;                      // 196*391 (int) per-(bucket,blk) counts
static const size_t OFF_OM   = OFF_CM   + (size_t)NBKT * NBLK;      // 196*391 (int) per-(bucket,blk) offsets
// total ~= 33.6 MB  (tmp aliases H: 800000*int2 = 6.4MB <= H's 12.8MB)

// Fold author linear into GAT1 weight; compute per-edge-attr scalar coefs.
__global__ void prep_kernel(const float* __restrict__ Wa, const float* __restrict__ ba,
                            const float* __restrict__ c1W,
                            const float* __restrict__ c1We, const float* __restrict__ c1ae,
                            const float* __restrict__ c2We, const float* __restrict__ c2ae,
                            float* __restrict__ W1c, float* __restrict__ b1c,
                            float* __restrict__ ce) {
    int t = threadIdx.x;
    for (int idx = t; idx < 64 * 64; idx += 256) {
        int i = idx >> 6, j = idx & 63;
        float s = 0.f;
        for (int k = 0; k < 64; ++k) s += Wa[i * 64 + k] * c1W[k * 64 + j];
        W1c[idx] = s;
    }
    if (t < 64) {
        float s = 0.f;
        for (int k = 0; k < 64; ++k) s += ba[k] * c1W[k * 64 + t];
        b1c[t] = s;
    }
    if (t == 64) {
        float s = 0.f;
        for (int k = 0; k < 64; ++k) s += c1We[k] * c1ae[k];
        ce[0] = s;
    }
    if (t == 65) {
        float s = 0.f;
        for (int k = 0; k < 64; ++k) s += c2We[k] * c2ae[k];
        ce[1] = s;
    }
}

// ---------------- per-node degree histogram (for row_ptr) ----------------
__global__ void hist_kernel(const int* __restrict__ ei, int* __restrict__ cnt) {
    int e = blockIdx.x * blockDim.x + threadIdx.x;
    if (e < N_EDGES) atomicAdd(&cnt[ei[N_EDGES + e]], 1);
}

// Parallel scan, phase A: per-block (256-wide) sums.
__global__ void block_sum_kernel(const int* __restrict__ cnt, int* __restrict__ bsum) {
    __shared__ int red[256];
    int t = threadIdx.x;
    int i = blockIdx.x * 256 + t;
    red[t] = (i < N_NODES) ? cnt[i] : 0;
    __syncthreads();
    for (int off = 128; off > 0; off >>= 1) {
        if (t < off) red[t] += red[t + off];
        __syncthreads();
    }
    if (t == 0) bsum[blockIdx.x] = red[0];
}

// Phase B: one block scans the 196 block sums -> exclusive bases (in place).
__global__ void scan_bsum_kernel(int* __restrict__ bsum) {
    __shared__ int s[256];
    int t = threadIdx.x;
    int v = (t < SCAN_BLOCKS) ? bsum[t] : 0;
    s[t] = v;
    __syncthreads();
    for (int off = 1; off < 256; off <<= 1) {
        int u = (t >= off) ? s[t - off] : 0;
        __syncthreads();
        s[t] += u;
        __syncthreads();
    }
    if (t < SCAN_BLOCKS) bsum[t] = s[t] - v;   // exclusive base
}

// Phase C: per-block inclusive scan + base -> exclusive row_ptr.
__global__ void scan_final_kernel(const int* __restrict__ cnt,
                                  const int* __restrict__ bsum,
                                  int* __restrict__ row_ptr) {
    __shared__ int s[256];
    int t = threadIdx.x;
    int i = blockIdx.x * 256 + t;
    int v = (i < N_NODES) ? cnt[i] : 0;
    s[t] = v;
    __syncthreads();
    for (int off = 1; off < 256; off <<= 1) {
        int u = (t >= off) ? s[t - off] : 0;
        __syncthreads();
        s[t] += u;
        __syncthreads();
    }
    int excl = s[t] - v + bsum[blockIdx.x];
    if (i < N_NODES) row_ptr[i] = excl;
    if (i == N_NODES - 1) row_ptr[N_NODES] = excl + v;
}

// ---------------- partition scatter (4 phases, no hot global atomics) ----
// Phase A: per-(input-block, bucket) histogram via LDS. bucket = dst >> 8.
__global__ void blkhist_kernel(const int* __restrict__ ei, int* __restrict__ countM) {
    __shared__ int lh[NBKT];
    int t = threadIdx.x, blk = blockIdx.x;
    if (t < NBKT) lh[t] = 0;
    __syncthreads();
    int base = blk * 2048;
#pragma unroll
    for (int i = 0; i < 8; ++i) {
        int e = base + i * 256 + t;
        if (e < N_EDGES) atomicAdd(&lh[ei[N_EDGES + e] >> 8], 1);
    }
    __syncthreads();
    if (t < NBKT) countM[t * NBLK + blk] = lh[t];
}

// Phase B: per-bucket exclusive scan over the 391 block-counts.
// Bucket base comes free from row_ptr (bucket b = nodes [256b, 256b+256)).
__global__ void bucket_scan_kernel(const int* __restrict__ countM,
                                   const int* __restrict__ row_ptr,
                                   int* __restrict__ offM) {
    __shared__ int s[256];
    int b = blockIdx.x, t = threadIdx.x;
    int i0 = 2 * t, i1 = 2 * t + 1;
    int c0 = (i0 < NBLK) ? countM[b * NBLK + i0] : 0;
    int c1 = (i1 < NBLK) ? countM[b * NBLK + i1] : 0;
    int own = c0 + c1;
    s[t] = own;
    __syncthreads();
    for (int off = 1; off < 256; off <<= 1) {
        int u = (t >= off) ? s[t - off] : 0;
        __syncthreads();
        s[t] += u;
        __syncthreads();
    }
    int excl = s[t] - own + row_ptr[b * 256];
    if (i0 < NBLK) offM[b * NBLK + i0] = excl;
    if (i1 < NBLK) offM[b * NBLK + i1] = excl + c0;
}

// Phase C: replay edges; LDS cursors hand out globally-unique bucket-ordered
// slots. Each (blk,bucket) run is contiguous and written by one CU -> merges.
__global__ void partition_kernel(const int* __restrict__ ei,
                                 const float* __restrict__ ea,
                                 const int* __restrict__ offM,
                                 int2* __restrict__ tmp) {
    __shared__ int lcur[NBKT];
    int t = threadIdx.x, blk = blockIdx.x;
    if (t < NBKT) lcur[t] = offM[t * NBLK + blk];
    __syncthreads();
    int base = blk * 2048;
#pragma unroll
    for (int i = 0; i < 8; ++i) {
        int e = base + i * 256 + t;
        if (e < N_EDGES) {
            int d = ei[N_EDGES + e];
            int pos = atomicAdd(&lcur[d >> 8], 1);
            int2 pr; pr.x = (d << 16) | ei[e]; pr.y = __float_as_int(ea[e]);
            tmp[pos] = pr;
        }
    }
}

// Phase D: fine placement. One block per bucket; the ~33KB CSR window stays
// in one XCD's L2 -> ~1x write amplification. Consumes cnt (ends at zero).
__global__ void place_kernel(const int2* __restrict__ tmp,
                             const int* __restrict__ row_ptr,
                             int* __restrict__ cnt,
                             int2* __restrict__ pack) {
    int b = blockIdx.x;
    int beg = row_ptr[b * 256];
    int endn = (b + 1) * 256; if (endn > N_NODES) endn = N_NODES;
    int end = row_ptr[endn];
    for (int pos = beg + threadIdx.x; pos < end; pos += blockDim.x) {
        int2 pr = tmp[pos];
        int d = ((unsigned)pr.x) >> 16;
        int old = atomicSub(&cnt[d], 1);       // old in [1..deg]
        int slot = row_ptr[d] + old - 1;
        int2 o; o.x = pr.x & 0xFFFF; o.y = pr.y;
        pack[slot] = o;
    }
}

// H = X @ W (+postb) ; Asrc = H . avs ; Adst = H . avd
// W column held in 64 VGPRs per lane; X row loaded at wave-uniform addresses.
__global__ void gemm_attn_kernel(const float* __restrict__ X,
                                 const float* __restrict__ W,
                                 const float* __restrict__ postb, int has_postb,
                                 const float* __restrict__ avs,
                                 const float* __restrict__ avd,
                                 float* __restrict__ H,
                                 float* __restrict__ Asrc, float* __restrict__ Adst) {
    int lane = threadIdx.x & 63;
    int wid  = __builtin_amdgcn_readfirstlane(threadIdx.x >> 6);  // uniform
    int gwave  = blockIdx.x * 4 + wid;
    int nwaves = gridDim.x * 4;
    float wcol[64];
#pragma unroll
    for (int k = 0; k < 64; ++k) wcol[k] = W[k * 64 + lane];
    float as_l = avs[lane], ad_l = avd[lane];
    float ob = has_postb ? postb[lane] : 0.f;
    for (int row = gwave; row < N_NODES; row += nwaves) {
        const float4* xr4 = (const float4*)(X + (size_t)row * 64);  // uniform addr
        float acc = ob;
#pragma unroll
        for (int i = 0; i < 16; ++i) {
            float4 xq = xr4[i];
            acc = fmaf(xq.x, wcol[4 * i + 0], acc);
            acc = fmaf(xq.y, wcol[4 * i + 1], acc);
            acc = fmaf(xq.z, wcol[4 * i + 2], acc);
            acc = fmaf(xq.w, wcol[4 * i + 3], acc);
        }
        H[(size_t)row * 64 + lane] = acc;
        float s1 = acc * as_l, s2 = acc * ad_l;
#pragma unroll
        for (int off = 32; off > 0; off >>= 1) {
            s1 += __shfl_xor(s1, off);
            s2 += __shfl_xor(s2, off);
        }
        if (lane == 0) { Asrc[row] = s1; Adst[row] = s2; }
    }
}

// Fused per-dst gather: alpha -> exp -> weighted sum -> normalize (+opt bias/relu).
// One wave per node: lane = 4 edge-subgroups x 16 feature-lanes (float4 each).
__global__ void aggregate_csr_kernel(const int* __restrict__ row_ptr,
                                     const int2* __restrict__ pack,
                                     const float* __restrict__ Asrc,
                                     const float* __restrict__ Adst,
                                     const float* __restrict__ cep,
                                     const float* __restrict__ H,
                                     float* __restrict__ Agg,
                                     const float* __restrict__ obias, int do_relu) {
    int t    = threadIdx.x;
    int q    = t & 15;          // feature quad (16 lanes x float4 = 64 feats)
    int sub  = (t >> 4) & 3;    // edge subgroup 0..3
    int wid  = t >> 6;          // wave in block
    int node = blockIdx.x * 4 + wid;
    if (node >= N_NODES) return;
    float ce = *cep;
    float ad = Adst[node];
    int beg = row_ptr[node], end = row_ptr[node + 1];
    float ax = 0.f, ay = 0.f, az = 0.f, aw = 0.f, accp = 0.f;
    for (int pos = beg + sub; pos < end; pos += 4) {
        int2  pr  = pack[pos];
        int   s   = pr.x;
        float ev  = __int_as_float(pr.y);
        float as_ = Asrc[s];
        float4 hv = *(const float4*)(H + (size_t)s * 64 + q * 4);
        float al = as_ + ad + ev * ce;
        al = al >= 0.f ? al : 0.2f * al;
        float p = __expf(al);
        ax += p * hv.x; ay += p * hv.y; az += p * hv.z; aw += p * hv.w;
        accp += p;
    }
    // reduce across the 4 edge-subgroups (lane = sub*16 + q): xor 16 then 32
    ax += __shfl_xor(ax, 16); ax += __shfl_xor(ax, 32);
    ay += __shfl_xor(ay, 16); ay += __shfl_xor(ay, 32);
    az += __shfl_xor(az, 16); az += __shfl_xor(az, 32);
    aw += __shfl_xor(aw, 16); aw += __shfl_xor(aw, 32);
    accp += __shfl_xor(accp, 16); accp += __shfl_xor(accp, 32);
    if (sub == 0) {
        float inv = 1.f / (accp + 1e-16f);
        float4 o; o.x = ax * inv; o.y = ay * inv; o.z = az * inv; o.w = aw * inv;
        if (obias) {
            float4 b = ((const float4*)obias)[q];
            o.x += b.x; o.y += b.y; o.z += b.z; o.w += b.w;
            if (do_relu) {
                o.x = fmaxf(o.x, 0.f); o.y = fmaxf(o.y, 0.f);
                o.z = fmaxf(o.z, 0.f); o.w = fmaxf(o.w, 0.f);
            }
        }
        *(float4*)(Agg + (size_t)node * 64 + q * 4) = o;
    }
}

// Edge classifier: out[e] = dot(Agg[i]+b, Agg[j]+b). 16-lane group per edge, float4.
__global__ void classify_kernel(const int* __restrict__ eli,
                                const float* __restrict__ Agg,
                                const float* __restrict__ bias,
                                float* __restrict__ out) {
    int t    = threadIdx.x;
    int q    = t & 15;
    int grp  = (blockIdx.x * blockDim.x + t) >> 4;
    if (grp >= N_LABEL) return;
    int e = grp;
    float4 b = ((const float4*)bias)[q];
    int i = eli[e], j = eli[N_LABEL + e];
    float4 a = ((const float4*)(Agg + (size_t)i * 64))[q];
    float4 c = ((const float4*)(Agg + (size_t)j * 64))[q];
    float s = (a.x + b.x) * (c.x + b.x) + (a.y + b.y) * (c.y + b.y) +
              (a.z + b.z) * (c.z + b.z) + (a.w + b.w) * (c.w + b.w);
#pragma unroll
    for (int off = 8; off > 0; off >>= 1) s += __shfl_xor(s, off);
    if (q == 0) out[e] = s;
}

extern "C" void kernel_launch(void* const* d_in, const int* in_sizes, int n_in,
                              void* d_out, int out_size, void* d_ws, size_t ws_size,
                              hipStream_t stream) {
    const float* x    = (const float*)d_in[0];
    const float* ea   = (const float*)d_in[1];
    const float* Wa   = (const float*)d_in[2];
    const float* ba   = (const float*)d_in[3];
    const float* c1W  = (const float*)d_in[4];
    const float* c1as = (const float*)d_in[5];
    const float* c1ad = (const float*)d_in[6];
    const float* c1We = (const float*)d_in[7];
    const float* c1ae = (const float*)d_in[8];
    const float* c1b  = (const float*)d_in[9];
    const float* c2W  = (const float*)d_in[10];
    const float* c2as = (const float*)d_in[11];
    const float* c2ad = (const float*)d_in[12];
    const float* c2We = (const float*)d_in[13];
    const float* c2ae = (const float*)d_in[14];
    const float* c2b  = (const float*)d_in[15];
    const int*   ei   = (const int*)d_in[16];
    const int*   eli  = (const int*)d_in[17];
    float* out = (float*)d_out;

    float* w    = (float*)d_ws;
    float* W1c  = w + OFF_W1C;
    float* b1c  = w + OFF_B1C;
    float* ce   = w + OFF_CE;
    float* H    = w + OFF_H;
    float* Agg  = w + OFF_AGG;
    float* Asrc = w + OFF_ASRC;
    float* Adst = w + OFF_ADST;
    int*   rowp = (int*)(w + OFF_ROW);
    int*   cnt  = (int*)(w + OFF_CNT);
    int2*  pack = (int2*)(w + OFF_PACK);
    int*   bsum = (int*)(w + OFF_BSUM);
    int*   cm   = (int*)(w + OFF_CM);
    int*   om   = (int*)(w + OFF_OM);
    int2*  tmp  = (int2*)(w + OFF_H);   // aliases H: dead until GEMM-1 (stream-ordered)

    // ---- prep + CSR build (structure shared by both layers) ----
    prep_kernel<<<1, 256, 0, stream>>>(Wa, ba, c1W, c1We, c1ae, c2We, c2ae,
                                       W1c, b1c, ce);
    hipMemsetAsync(cnt, 0, (size_t)N_NODES * sizeof(int), stream);
    hist_kernel<<<(N_EDGES + 255) / 256, 256, 0, stream>>>(ei, cnt);
    block_sum_kernel<<<SCAN_BLOCKS, 256, 0, stream>>>(cnt, bsum);
    scan_bsum_kernel<<<1, 256, 0, stream>>>(bsum);
    scan_final_kernel<<<SCAN_BLOCKS, 256, 0, stream>>>(cnt, bsum, rowp);
    blkhist_kernel<<<NBLK, 256, 0, stream>>>(ei, cm);
    bucket_scan_kernel<<<NBKT, 256, 0, stream>>>(cm, rowp, om);
    partition_kernel<<<NBLK, 256, 0, stream>>>(ei, ea, om, tmp);
    place_kernel<<<NBKT, 256, 0, stream>>>(tmp, rowp, cnt, pack);

    // ---- layer 1: H1 = x @ W1c + b1c ; agg1 = softmax-agg(H1) + c1b, relu ----
    gemm_attn_kernel<<<1024, 256, 0, stream>>>(x, W1c, b1c, 1,
                                               c1as, c1ad, H, Asrc, Adst);
    aggregate_csr_kernel<<<12500, 256, 0, stream>>>(rowp, pack, Asrc, Adst,
                                                    ce + 0, H, Agg, c1b, 1);

    // ---- layer 2: H2 = agg1 @ c2W ; agg2 = softmax-agg(H2) ----
    gemm_attn_kernel<<<1024, 256, 0, stream>>>(Agg, c2W, nullptr, 0,
                                               c2as, c2ad, H, Asrc, Adst);
    aggregate_csr_kernel<<<12500, 256, 0, stream>>>(rowp, pack, Asrc, Adst,
                                                    ce + 1, H, Agg, nullptr, 0);

    // ---- classifier (adds c2b to both operands) ----
    classify_kernel<<<(N_LABEL * 16 + 255) / 256, 256, 0, stream>>>(eli, Agg, c2b, out);
}

// Round 16
// 276.411 us; speedup vs baseline: 1.7196x; 1.1713x over previous
//
#include <hip/hip_runtime.h>

#define N_NODES 50000
#define N_EDGES 800000
#define N_LABEL 200000
#define HID 64
#define NBKT 196          // dst >> 8  (256 nodes per bucket)
#define NBLK 391          // ceil(800000/2048) input blocks of 2048 edges

// ---------------- ws layout (4-byte units) ----------------
static const size_t OFF_W1C  = 0;                                   // 64*64
static const size_t OFF_B1C  = 4096;                                // 64
static const size_t OFF_CE   = 4160;                                // 2 (pad to 4224)
static const size_t OFF_H    = 4224;                                // 50000*64 (aliases int2 tmp[800000] during CSR build)
static const size_t OFF_AGG  = OFF_H    + (size_t)N_NODES * HID;    // 50000*64
static const size_t OFF_ASRC = OFF_AGG  + (size_t)N_NODES * HID;    // 50000
static const size_t OFF_ADST = OFF_ASRC + (size_t)N_NODES;          // 50000
static const size_t OFF_ROW  = OFF_ADST + (size_t)N_NODES;          // 50002 (int, padded even)
static const size_t OFF_PACK = OFF_ROW  + (size_t)N_NODES + 2;      // 2*800000 (int2), 8B-aligned (offset even)
static const size_t OFF_CM   = OFF_PACK + 2 * (size_t)N_EDGES;      // 196*391 (int) per-(bucket,blk) counts
static const size_t OFF_OM   = OFF_CM   + (size_t)NBKT * NBLK;      // 196*391 (int) per-(bucket,blk) offsets
static const size_t OFF_BKB  = OFF_OM   + (size_t)NBKT * NBLK;      // 197 (int) bucket bases in edge array
// total ~= 33.2 MB  (tmp aliases H: 800000*int2 = 6.4MB <= H's 12.8MB)

// ---- Phase 1: per-(input-block, bucket) histogram via LDS; block 0 also
// folds author linear into GAT1 weight + edge-attr scalar coefs (prep).
__global__ void blkhist_prep_kernel(const int* __restrict__ ei, int* __restrict__ countM,
                                    const float* __restrict__ Wa, const float* __restrict__ ba,
                                    const float* __restrict__ c1W,
                                    const float* __restrict__ c1We, const float* __restrict__ c1ae,
                                    const float* __restrict__ c2We, const float* __restrict__ c2ae,
                                    float* __restrict__ W1c, float* __restrict__ b1c,
                                    float* __restrict__ ce) {
    __shared__ int lh[NBKT];
    int t = threadIdx.x, blk = blockIdx.x;
    if (t < NBKT) lh[t] = 0;
    __syncthreads();
    int base = blk * 2048;
#pragma unroll
    for (int i = 0; i < 8; ++i) {
        int e = base + i * 256 + t;
        if (e < N_EDGES) atomicAdd(&lh[ei[N_EDGES + e] >> 8], 1);
    }
    __syncthreads();
    if (t < NBKT) countM[t * NBLK + blk] = lh[t];
    if (blk == 0) {
        for (int idx = t; idx < 64 * 64; idx += 256) {
            int i = idx >> 6, j = idx & 63;
            float s = 0.f;
            for (int k = 0; k < 64; ++k) s += Wa[i * 64 + k] * c1W[k * 64 + j];
            W1c[idx] = s;
        }
        if (t < 64) {
            float s = 0.f;
            for (int k = 0; k < 64; ++k) s += ba[k] * c1W[k * 64 + t];
            b1c[t] = s;
        }
        if (t == 64) {
            float s = 0.f;
            for (int k = 0; k < 64; ++k) s += c1We[k] * c1ae[k];
            ce[0] = s;
        }
        if (t == 65) {
            float s = 0.f;
            for (int k = 0; k < 64; ++k) s += c2We[k] * c2ae[k];
            ce[1] = s;
        }
    }
}

// ---- Phase 2: block b computes its bucket base (sum of buckets < b, L2-hot)
// then exclusive-scans its 391 block-counts -> offM; emits bktbase[b] (+[NBKT]).
__global__ void bucket_scan_kernel(const int* __restrict__ countM,
                                   int* __restrict__ offM,
                                   int* __restrict__ bktbase) {
    __shared__ int s[256];
    int b = blockIdx.x, t = threadIdx.x;
    // (a) base = sum over buckets j < b (each thread handles at most one row here)
    int part = 0;
    for (int j = t; j < b; j += 256) {
        const int* row = countM + (size_t)j * NBLK;
        int rs = 0;
        for (int i = 0; i < NBLK; ++i) rs += row[i];
        part += rs;
    }
    s[t] = part;
    __syncthreads();
    for (int off = 128; off > 0; off >>= 1) {
        if (t < off) s[t] += s[t + off];
        __syncthreads();
    }
    int base = s[0];
    __syncthreads();                       // s reused below
    // (b) exclusive scan of this bucket's 391 block-counts (2 per thread)
    int i0 = 2 * t, i1 = 2 * t + 1;
    int c0 = (i0 < NBLK) ? countM[b * NBLK + i0] : 0;
    int c1 = (i1 < NBLK) ? countM[b * NBLK + i1] : 0;
    int own = c0 + c1;
    s[t] = own;
    __syncthreads();
    for (int off = 1; off < 256; off <<= 1) {
        int u = (t >= off) ? s[t - off] : 0;
        __syncthreads();
        s[t] += u;
        __syncthreads();
    }
    int excl = s[t] - own + base;
    if (i0 < NBLK) offM[b * NBLK + i0] = excl;
    if (i1 < NBLK) offM[b * NBLK + i1] = excl + c0;
    if (t == 255) {
        if (b == 0) bktbase[0] = 0;
        bktbase[b + 1] = base + s[255];    // end of bucket b (b<NBKT-1: start of b+1)
    }
    if (t == 0 && b > 0) bktbase[b] = base;
}

// ---- Phase 3: replay edges; LDS cursors hand out globally-unique
// bucket-ordered slots; each (blk,bucket) run is contiguous -> writes merge.
__global__ void partition_kernel(const int* __restrict__ ei,
                                 const float* __restrict__ ea,
                                 const int* __restrict__ offM,
                                 int2* __restrict__ tmp) {
    __shared__ int lcur[NBKT];
    int t = threadIdx.x, blk = blockIdx.x;
    if (t < NBKT) lcur[t] = offM[t * NBLK + blk];
    __syncthreads();
    int base = blk * 2048;
#pragma unroll
    for (int i = 0; i < 8; ++i) {
        int e = base + i * 256 + t;
        if (e < N_EDGES) {
            int d = ei[N_EDGES + e];
            int pos = atomicAdd(&lcur[d >> 8], 1);
            int2 pr; pr.x = (d << 16) | ei[e]; pr.y = __float_as_int(ea[e]);
            tmp[pos] = pr;
        }
    }
}

// ---- Phase 4: one block per bucket. Derive per-node degrees from tmp (LDS),
// LDS-scan -> write this bucket's row_ptr segment, then place pack entries
// via LDS cursors. No global per-node counter, ~33KB L2-local window.
__global__ void place_rowptr_kernel(const int2* __restrict__ tmp,
                                    const int* __restrict__ bktbase,
                                    int* __restrict__ row_ptr,
                                    int2* __restrict__ pack) {
    __shared__ int deg[256];
    __shared__ int s[256];
    __shared__ int cur[256];
    int b = blockIdx.x, t = threadIdx.x;
    int beg = bktbase[b], end = bktbase[b + 1];
    deg[t] = 0;
    __syncthreads();
    for (int pos = beg + t; pos < end; pos += 256)
        atomicAdd(&deg[(((unsigned)tmp[pos].x) >> 16) & 255], 1);
    __syncthreads();
    int v = deg[t];
    s[t] = v;
    __syncthreads();
    for (int off = 1; off < 256; off <<= 1) {
        int u = (t >= off) ? s[t - off] : 0;
        __syncthreads();
        s[t] += u;
        __syncthreads();
    }
    int excl = s[t] - v;
    int node = b * 256 + t;
    if (node < N_NODES) row_ptr[node] = beg + excl;
    if (node == N_NODES - 1) row_ptr[N_NODES] = beg + excl + v;
    cur[t] = beg + excl;
    __syncthreads();
    for (int pos = beg + t; pos < end; pos += 256) {
        int2 pr = tmp[pos];
        int d = ((unsigned)pr.x) >> 16;
        int slot = atomicAdd(&cur[d & 255], 1);
        int2 o; o.x = pr.x & 0xFFFF; o.y = pr.y;
        pack[slot] = o;
    }
}

// H = X @ W (+postb) ; Asrc = H . avs ; Adst = H . avd
// W column held in 64 VGPRs per lane; X row loaded at wave-uniform addresses.
__global__ void gemm_attn_kernel(const float* __restrict__ X,
                                 const float* __restrict__ W,
                                 const float* __restrict__ postb, int has_postb,
                                 const float* __restrict__ avs,
                                 const float* __restrict__ avd,
                                 float* __restrict__ H,
                                 float* __restrict__ Asrc, float* __restrict__ Adst) {
    int lane = threadIdx.x & 63;
    int wid  = __builtin_amdgcn_readfirstlane(threadIdx.x >> 6);  // uniform
    int gwave  = blockIdx.x * 4 + wid;
    int nwaves = gridDim.x * 4;
    float wcol[64];
#pragma unroll
    for (int k = 0; k < 64; ++k) wcol[k] = W[k * 64 + lane];
    float as_l = avs[lane], ad_l = avd[lane];
    float ob = has_postb ? postb[lane] : 0.f;
    for (int row = gwave; row < N_NODES; row += nwaves) {
        const float4* xr4 = (const float4*)(X + (size_t)row * 64);  // uniform addr
        float acc = ob;
#pragma unroll
        for (int i = 0; i < 16; ++i) {
            float4 xq = xr4[i];
            acc = fmaf(xq.x, wcol[4 * i + 0], acc);
            acc = fmaf(xq.y, wcol[4 * i + 1], acc);
            acc = fmaf(xq.z, wcol[4 * i + 2], acc);
            acc = fmaf(xq.w, wcol[4 * i + 3], acc);
        }
        H[(size_t)row * 64 + lane] = acc;
        float s1 = acc * as_l, s2 = acc * ad_l;
#pragma unroll
        for (int off = 32; off > 0; off >>= 1) {
            s1 += __shfl_xor(s1, off);
            s2 += __shfl_xor(s2, off);
        }
        if (lane == 0) { Asrc[row] = s1; Adst[row] = s2; }
    }
}

// Fused per-dst gather: alpha -> exp -> weighted sum -> normalize (+opt bias/relu).
// One wave per node: lane = 4 edge-subgroups x 16 feature-lanes (float4 each).
__global__ void aggregate_csr_kernel(const int* __restrict__ row_ptr,
                                     const int2* __restrict__ pack,
                                     const float* __restrict__ Asrc,
                                     const float* __restrict__ Adst,
                                     const float* __restrict__ cep,
                                     const float* __restrict__ H,
                                     float* __restrict__ Agg,
                                     const float* __restrict__ obias, int do_relu) {
    int t    = threadIdx.x;
    int q    = t & 15;          // feature quad (16 lanes x float4 = 64 feats)
    int sub  = (t >> 4) & 3;    // edge subgroup 0..3
    int wid  = t >> 6;          // wave in block
    int node = blockIdx.x * 4 + wid;
    if (node >= N_NODES) return;
    float ce = *cep;
    float ad = Adst[node];
    int beg = row_ptr[node], end = row_ptr[node + 1];
    float ax = 0.f, ay = 0.f, az = 0.f, aw = 0.f, accp = 0.f;
    for (int pos = beg + sub; pos < end; pos += 4) {
        int2  pr  = pack[pos];
        int   s   = pr.x;
        float ev  = __int_as_float(pr.y);
        float as_ = Asrc[s];
        float4 hv = *(const float4*)(H + (size_t)s * 64 + q * 4);
        float al = as_ + ad + ev * ce;
        al = al >= 0.f ? al : 0.2f * al;
        float p = __expf(al);
        ax += p * hv.x; ay += p * hv.y; az += p * hv.z; aw += p * hv.w;
        accp += p;
    }
    // reduce across the 4 edge-subgroups (lane = sub*16 + q): xor 16 then 32
    ax += __shfl_xor(ax, 16); ax += __shfl_xor(ax, 32);
    ay += __shfl_xor(ay, 16); ay += __shfl_xor(ay, 32);
    az += __shfl_xor(az, 16); az += __shfl_xor(az, 32);
    aw += __shfl_xor(aw, 16); aw += __shfl_xor(aw, 32);
    accp += __shfl_xor(accp, 16); accp += __shfl_xor(accp, 32);
    if (sub == 0) {
        float inv = 1.f / (accp + 1e-16f);
        float4 o; o.x = ax * inv; o.y = ay * inv; o.z = az * inv; o.w = aw * inv;
        if (obias) {
            float4 b = ((const float4*)obias)[q];
            o.x += b.x; o.y += b.y; o.z += b.z; o.w += b.w;
            if (do_relu) {
                o.x = fmaxf(o.x, 0.f); o.y = fmaxf(o.y, 0.f);
                o.z = fmaxf(o.z, 0.f); o.w = fmaxf(o.w, 0.f);
            }
        }
        *(float4*)(Agg + (size_t)node * 64 + q * 4) = o;
    }
}

// Edge classifier: out[e] = dot(Agg[i]+b, Agg[j]+b). 16-lane group per edge, float4.
__global__ void classify_kernel(const int* __restrict__ eli,
                                const float* __restrict__ Agg,
                                const float* __restrict__ bias,
                                float* __restrict__ out) {
    int t    = threadIdx.x;
    int q    = t & 15;
    int grp  = (blockIdx.x * blockDim.x + t) >> 4;
    if (grp >= N_LABEL) return;
    int e = grp;
    float4 b = ((const float4*)bias)[q];
    int i = eli[e], j = eli[N_LABEL + e];
    float4 a = ((const float4*)(Agg + (size_t)i * 64))[q];
    float4 c = ((const float4*)(Agg + (size_t)j * 64))[q];
    float s = (a.x + b.x) * (c.x + b.x) + (a.y + b.y) * (c.y + b.y) +
              (a.z + b.z) * (c.z + b.z) + (a.w + b.w) * (c.w + b.w);
#pragma unroll
    for (int off = 8; off > 0; off >>= 1) s += __shfl_xor(s, off);
    if (q == 0) out[e] = s;
}

extern "C" void kernel_launch(void* const* d_in, const int* in_sizes, int n_in,
                              void* d_out, int out_size, void* d_ws, size_t ws_size,
                              hipStream_t stream) {
    const float* x    = (const float*)d_in[0];
    const float* ea   = (const float*)d_in[1];
    const float* Wa   = (const float*)d_in[2];
    const float* ba   = (const float*)d_in[3];
    const float* c1W  = (const float*)d_in[4];
    const float* c1as = (const float*)d_in[5];
    const float* c1ad = (const float*)d_in[6];
    const float* c1We = (const float*)d_in[7];
    const float* c1ae = (const float*)d_in[8];
    const float* c1b  = (const float*)d_in[9];
    const float* c2W  = (const float*)d_in[10];
    const float* c2as = (const float*)d_in[11];
    const float* c2ad = (const float*)d_in[12];
    const float* c2We = (const float*)d_in[13];
    const float* c2ae = (const float*)d_in[14];
    const float* c2b  = (const float*)d_in[15];
    const int*   ei   = (const int*)d_in[16];
    const int*   eli  = (const int*)d_in[17];
    float* out = (float*)d_out;

    float* w    = (float*)d_ws;
    float* W1c  = w + OFF_W1C;
    float* b1c  = w + OFF_B1C;
    float* ce   = w + OFF_CE;
    float* H    = w + OFF_H;
    float* Agg  = w + OFF_AGG;
    float* Asrc = w + OFF_ASRC;
    float* Adst = w + OFF_ADST;
    int*   rowp = (int*)(w + OFF_ROW);
    int2*  pack = (int2*)(w + OFF_PACK);
    int*   cm   = (int*)(w + OFF_CM);
    int*   om   = (int*)(w + OFF_OM);
    int*   bkb  = (int*)(w + OFF_BKB);
    int2*  tmp  = (int2*)(w + OFF_H);   // aliases H: dead until GEMM-1 (stream-ordered)

    // ---- CSR build (4 dispatches; structure shared by both layers) ----
    blkhist_prep_kernel<<<NBLK, 256, 0, stream>>>(ei, cm, Wa, ba, c1W,
                                                  c1We, c1ae, c2We, c2ae,
                                                  W1c, b1c, ce);
    bucket_scan_kernel<<<NBKT, 256, 0, stream>>>(cm, om, bkb);
    partition_kernel<<<NBLK, 256, 0, stream>>>(ei, ea, om, tmp);
    place_rowptr_kernel<<<NBKT, 256, 0, stream>>>(tmp, bkb, rowp, pack);

    // ---- layer 1: H1 = x @ W1c + b1c ; agg1 = softmax-agg(H1) + c1b, relu ----
    gemm_attn_kernel<<<1024, 256, 0, stream>>>(x, W1c, b1c, 1,
                                               c1as, c1ad, H, Asrc, Adst);
    aggregate_csr_kernel<<<12500, 256, 0, stream>>>(rowp, pack, Asrc, Adst,
                                                    ce + 0, H, Agg, c1b, 1);

    // ---- layer 2: H2 = agg1 @ c2W ; agg2 = softmax-agg(H2) ----
    gemm_attn_kernel<<<1024, 256, 0, stream>>>(Agg, c2W, nullptr, 0,
                                               c2as, c2ad, H, Asrc, Adst);
    aggregate_csr_kernel<<<12500, 256, 0, stream>>>(rowp, pack, Asrc, Adst,
                                                    ce + 1, H, Agg, nullptr, 0);

    // ---- classifier (adds c2b to both operands) ----
    classify_kernel<<<(N_LABEL * 16 + 255) / 256, 256, 0, stream>>>(eli, Agg, c2b, out);
}

// Round 17
// 275.976 us; speedup vs baseline: 1.7223x; 1.0016x over previous
//
#include <hip/hip_runtime.h>

#define N_NODES 50000
#define N_EDGES 800000
#define N_LABEL 200000
#define HID 64
#define NBKT 196          // dst >> 8  (256 nodes per bucket)
#define NBLK 391          // ceil(800000/2048) input blocks of 2048 edges

// ---------------- ws layout (4-byte units) ----------------
static const size_t OFF_W1C  = 0;                                   // 64*64
static const size_t OFF_B1C  = 4096;                                // 64
static const size_t OFF_CE   = 4160;                                // 2 (pad to 4224)
static const size_t OFF_H    = 4224;                                // 50000*64 (aliases int2 tmp[800000] during CSR build)
static const size_t OFF_AGG  = OFF_H    + (size_t)N_NODES * HID;    // 50000*64
static const size_t OFF_ASRC = OFF_AGG  + (size_t)N_NODES * HID;    // 50000
static const size_t OFF_ADST = OFF_ASRC + (size_t)N_NODES;          // 50000
static const size_t OFF_ROW  = OFF_ADST + (size_t)N_NODES;          // 50002 (int, padded even)
static const size_t OFF_PACK = OFF_ROW  + (size_t)N_NODES + 2;      // 2*800000 (int2), 8B-aligned (offset even)
static const size_t OFF_CM   = OFF_PACK + 2 * (size_t)N_EDGES;      // 196*391 (int) per-(bucket,blk) counts
static const size_t OFF_OM   = OFF_CM   + (size_t)NBKT * NBLK;      // 196*391 (int) per-(bucket,blk) offsets
static const size_t OFF_BKB  = OFF_OM   + (size_t)NBKT * NBLK;      // 197 (int) bucket bases in edge array
// total ~= 33.2 MB  (tmp aliases H: 800000*int2 = 6.4MB <= H's 12.8MB)

// ---- Phase 1: per-(input-block, bucket) histogram via LDS; block 0 also
// folds author linear into GAT1 weight + edge-attr scalar coefs (prep).
__global__ void blkhist_prep_kernel(const int* __restrict__ ei, int* __restrict__ countM,
                                    const float* __restrict__ Wa, const float* __restrict__ ba,
                                    const float* __restrict__ c1W,
                                    const float* __restrict__ c1We, const float* __restrict__ c1ae,
                                    const float* __restrict__ c2We, const float* __restrict__ c2ae,
                                    float* __restrict__ W1c, float* __restrict__ b1c,
                                    float* __restrict__ ce) {
    __shared__ int lh[NBKT];
    int t = threadIdx.x, blk = blockIdx.x;
    if (t < NBKT) lh[t] = 0;
    __syncthreads();
    int base = blk * 2048;
#pragma unroll
    for (int i = 0; i < 8; ++i) {
        int e = base + i * 256 + t;
        if (e < N_EDGES) atomicAdd(&lh[ei[N_EDGES + e] >> 8], 1);
    }
    __syncthreads();
    if (t < NBKT) countM[t * NBLK + blk] = lh[t];
    if (blk == 0) {
        for (int idx = t; idx < 64 * 64; idx += 256) {
            int i = idx >> 6, j = idx & 63;
            float s = 0.f;
            for (int k = 0; k < 64; ++k) s += Wa[i * 64 + k] * c1W[k * 64 + j];
            W1c[idx] = s;
        }
        if (t < 64) {
            float s = 0.f;
            for (int k = 0; k < 64; ++k) s += ba[k] * c1W[k * 64 + t];
            b1c[t] = s;
        }
        if (t == 64) {
            float s = 0.f;
            for (int k = 0; k < 64; ++k) s += c1We[k] * c1ae[k];
            ce[0] = s;
        }
        if (t == 65) {
            float s = 0.f;
            for (int k = 0; k < 64; ++k) s += c2We[k] * c2ae[k];
            ce[1] = s;
        }
    }
}

// ---- Phase 2: block b computes its bucket base (sum of buckets < b, L2-hot)
// then exclusive-scans its 391 block-counts -> offM; emits bktbase[b] (+[NBKT]).
__global__ void bucket_scan_kernel(const int* __restrict__ countM,
                                   int* __restrict__ offM,
                                   int* __restrict__ bktbase) {
    __shared__ int s[256];
    int b = blockIdx.x, t = threadIdx.x;
    // (a) base = sum over buckets j < b (each thread handles at most one row here)
    int part = 0;
    for (int j = t; j < b; j += 256) {
        const int* row = countM + (size_t)j * NBLK;
        int rs = 0;
        for (int i = 0; i < NBLK; ++i) rs += row[i];
        part += rs;
    }
    s[t] = part;
    __syncthreads();
    for (int off = 128; off > 0; off >>= 1) {
        if (t < off) s[t] += s[t + off];
        __syncthreads();
    }
    int base = s[0];
    __syncthreads();                       // s reused below
    // (b) exclusive scan of this bucket's 391 block-counts (2 per thread)
    int i0 = 2 * t, i1 = 2 * t + 1;
    int c0 = (i0 < NBLK) ? countM[b * NBLK + i0] : 0;
    int c1 = (i1 < NBLK) ? countM[b * NBLK + i1] : 0;
    int own = c0 + c1;
    s[t] = own;
    __syncthreads();
    for (int off = 1; off < 256; off <<= 1) {
        int u = (t >= off) ? s[t - off] : 0;
        __syncthreads();
        s[t] += u;
        __syncthreads();
    }
    int excl = s[t] - own + base;
    if (i0 < NBLK) offM[b * NBLK + i0] = excl;
    if (i1 < NBLK) offM[b * NBLK + i1] = excl + c0;
    if (t == 255) {
        if (b == 0) bktbase[0] = 0;
        bktbase[b + 1] = base + s[255];    // end of bucket b (b<NBKT-1: start of b+1)
    }
    if (t == 0 && b > 0) bktbase[b] = base;
}

// ---- Phase 3: replay edges; LDS cursors hand out globally-unique
// bucket-ordered slots; each (blk,bucket) run is contiguous -> writes merge.
__global__ void partition_kernel(const int* __restrict__ ei,
                                 const float* __restrict__ ea,
                                 const int* __restrict__ offM,
                                 int2* __restrict__ tmp) {
    __shared__ int lcur[NBKT];
    int t = threadIdx.x, blk = blockIdx.x;
    if (t < NBKT) lcur[t] = offM[t * NBLK + blk];
    __syncthreads();
    int base = blk * 2048;
#pragma unroll
    for (int i = 0; i < 8; ++i) {
        int e = base + i * 256 + t;
        if (e < N_EDGES) {
            int d = ei[N_EDGES + e];
            int pos = atomicAdd(&lcur[d >> 8], 1);
            int2 pr; pr.x = (d << 16) | ei[e]; pr.y = __float_as_int(ea[e]);
            tmp[pos] = pr;
        }
    }
}

// ---- Phase 4: one block per bucket. Derive per-node degrees from tmp (LDS),
// LDS-scan -> write this bucket's row_ptr segment, then place pack entries
// via LDS cursors. No global per-node counter, ~33KB L2-local window.
__global__ void place_rowptr_kernel(const int2* __restrict__ tmp,
                                    const int* __restrict__ bktbase,
                                    int* __restrict__ row_ptr,
                                    int2* __restrict__ pack) {
    __shared__ int deg[256];
    __shared__ int s[256];
    __shared__ int cur[256];
    int b = blockIdx.x, t = threadIdx.x;
    int beg = bktbase[b], end = bktbase[b + 1];
    deg[t] = 0;
    __syncthreads();
    for (int pos = beg + t; pos < end; pos += 256)
        atomicAdd(&deg[(((unsigned)tmp[pos].x) >> 16) & 255], 1);
    __syncthreads();
    int v = deg[t];
    s[t] = v;
    __syncthreads();
    for (int off = 1; off < 256; off <<= 1) {
        int u = (t >= off) ? s[t - off] : 0;
        __syncthreads();
        s[t] += u;
        __syncthreads();
    }
    int excl = s[t] - v;
    int node = b * 256 + t;
    if (node < N_NODES) row_ptr[node] = beg + excl;
    if (node == N_NODES - 1) row_ptr[N_NODES] = beg + excl + v;
    cur[t] = beg + excl;
    __syncthreads();
    for (int pos = beg + t; pos < end; pos += 256) {
        int2 pr = tmp[pos];
        int d = ((unsigned)pr.x) >> 16;
        int slot = atomicAdd(&cur[d & 255], 1);
        int2 o; o.x = pr.x & 0xFFFF; o.y = pr.y;
        pack[slot] = o;
    }
}

// H = X @ W (+postb) ; Asrc = H . avs ; Adst = H . avd
// W column held in 64 VGPRs per lane; X row loaded at wave-uniform addresses.
__global__ void gemm_attn_kernel(const float* __restrict__ X,
                                 const float* __restrict__ W,
                                 const float* __restrict__ postb, int has_postb,
                                 const float* __restrict__ avs,
                                 const float* __restrict__ avd,
                                 float* __restrict__ H,
                                 float* __restrict__ Asrc, float* __restrict__ Adst) {
    int lane = threadIdx.x & 63;
    int wid  = __builtin_amdgcn_readfirstlane(threadIdx.x >> 6);  // uniform
    int gwave  = blockIdx.x * 4 + wid;
    int nwaves = gridDim.x * 4;
    float wcol[64];
#pragma unroll
    for (int k = 0; k < 64; ++k) wcol[k] = W[k * 64 + lane];
    float as_l = avs[lane], ad_l = avd[lane];
    float ob = has_postb ? postb[lane] : 0.f;
    for (int row = gwave; row < N_NODES; row += nwaves) {
        const float4* xr4 = (const float4*)(X + (size_t)row * 64);  // uniform addr
        float acc = ob;
#pragma unroll
        for (int i = 0; i < 16; ++i) {
            float4 xq = xr4[i];
            acc = fmaf(xq.x, wcol[4 * i + 0], acc);
            acc = fmaf(xq.y, wcol[4 * i + 1], acc);
            acc = fmaf(xq.z, wcol[4 * i + 2], acc);
            acc = fmaf(xq.w, wcol[4 * i + 3], acc);
        }
        H[(size_t)row * 64 + lane] = acc;
        float s1 = acc * as_l, s2 = acc * ad_l;
#pragma unroll
        for (int off = 32; off > 0; off >>= 1) {
            s1 += __shfl_xor(s1, off);
            s2 += __shfl_xor(s2, off);
        }
        if (lane == 0) { Asrc[row] = s1; Adst[row] = s2; }
    }
}

// Fused per-dst gather with 2-deep software pipeline: issue iteration i+1's
// pack/Asrc/H loads before consuming iteration i (doubles chains in flight).
// One wave per node: lane = 4 edge-subgroups x 16 feature-lanes (float4 each).
__global__ void aggregate_csr_kernel(const int* __restrict__ row_ptr,
                                     const int2* __restrict__ pack,
                                     const float* __restrict__ Asrc,
                                     const float* __restrict__ Adst,
                                     const float* __restrict__ cep,
                                     const float* __restrict__ H,
                                     float* __restrict__ Agg,
                                     const float* __restrict__ obias, int do_relu) {
    int t    = threadIdx.x;
    int q    = t & 15;          // feature quad (16 lanes x float4 = 64 feats)
    int sub  = (t >> 4) & 3;    // edge subgroup 0..3
    int wid  = t >> 6;          // wave in block
    int node = blockIdx.x * 4 + wid;
    if (node >= N_NODES) return;
    float ce = *cep;
    float ad = Adst[node];
    int beg = row_ptr[node], end = row_ptr[node + 1];
    float ax = 0.f, ay = 0.f, az = 0.f, aw = 0.f, accp = 0.f;

    int pos = beg + sub;
    bool v0 = pos < end;
    int2 pr0 = make_int2(0, 0);
    float as0 = 0.f;
    float4 hv0 = make_float4(0.f, 0.f, 0.f, 0.f);
    if (v0) {
        pr0 = pack[pos];
        as0 = Asrc[pr0.x];
        hv0 = *(const float4*)(H + (size_t)pr0.x * 64 + q * 4);
    }
    int2 pr1 = make_int2(0, 0);
    float as1 = 0.f;
    float4 hv1 = make_float4(0.f, 0.f, 0.f, 0.f);
    while (v0) {
        int npos = pos + 4;
        bool v1 = npos < end;
        if (v1) {                       // prefetch next iteration's chain
            pr1 = pack[npos];
            as1 = Asrc[pr1.x];
            hv1 = *(const float4*)(H + (size_t)pr1.x * 64 + q * 4);
        }
        float ev = __int_as_float(pr0.y);
        float al = as0 + ad + ev * ce;
        al = al >= 0.f ? al : 0.2f * al;
        float p = __expf(al);
        ax += p * hv0.x; ay += p * hv0.y; az += p * hv0.z; aw += p * hv0.w;
        accp += p;
        pr0 = pr1; as0 = as1; hv0 = hv1; v0 = v1; pos = npos;
    }
    // reduce across the 4 edge-subgroups (lane = sub*16 + q): xor 16 then 32
    ax += __shfl_xor(ax, 16); ax += __shfl_xor(ax, 32);
    ay += __shfl_xor(ay, 16); ay += __shfl_xor(ay, 32);
    az += __shfl_xor(az, 16); az += __shfl_xor(az, 32);
    aw += __shfl_xor(aw, 16); aw += __shfl_xor(aw, 32);
    accp += __shfl_xor(accp, 16); accp += __shfl_xor(accp, 32);
    if (sub == 0) {
        float inv = 1.f / (accp + 1e-16f);
        float4 o; o.x = ax * inv; o.y = ay * inv; o.z = az * inv; o.w = aw * inv;
        if (obias) {
            float4 b = ((const float4*)obias)[q];
            o.x += b.x; o.y += b.y; o.z += b.z; o.w += b.w;
            if (do_relu) {
                o.x = fmaxf(o.x, 0.f); o.y = fmaxf(o.y, 0.f);
                o.z = fmaxf(o.z, 0.f); o.w = fmaxf(o.w, 0.f);
            }
        }
        *(float4*)(Agg + (size_t)node * 64 + q * 4) = o;
    }
}

// Edge classifier: out[e] = dot(Agg[i]+b, Agg[j]+b). 16-lane group per edge, float4.
__global__ void classify_kernel(const int* __restrict__ eli,
                                const float* __restrict__ Agg,
                                const float* __restrict__ bias,
                                float* __restrict__ out) {
    int t    = threadIdx.x;
    int q    = t & 15;
    int grp  = (blockIdx.x * blockDim.x + t) >> 4;
    if (grp >= N_LABEL) return;
    int e = grp;
    float4 b = ((const float4*)bias)[q];
    int i = eli[e], j = eli[N_LABEL + e];
    float4 a = ((const float4*)(Agg + (size_t)i * 64))[q];
    float4 c = ((const float4*)(Agg + (size_t)j * 64))[q];
    float s = (a.x + b.x) * (c.x + b.x) + (a.y + b.y) * (c.y + b.y) +
              (a.z + b.z) * (c.z + b.z) + (a.w + b.w) * (c.w + b.w);
#pragma unroll
    for (int off = 8; off > 0; off >>= 1) s += __shfl_xor(s, off);
    if (q == 0) out[e] = s;
}

extern "C" void kernel_launch(void* const* d_in, const int* in_sizes, int n_in,
                              void* d_out, int out_size, void* d_ws, size_t ws_size,
                              hipStream_t stream) {
    const float* x    = (const float*)d_in[0];
    const float* ea   = (const float*)d_in[1];
    const float* Wa   = (const float*)d_in[2];
    const float* ba   = (const float*)d_in[3];
    const float* c1W  = (const float*)d_in[4];
    const float* c1as = (const float*)d_in[5];
    const float* c1ad = (const float*)d_in[6];
    const float* c1We = (const float*)d_in[7];
    const float* c1ae = (const float*)d_in[8];
    const float* c1b  = (const float*)d_in[9];
    const float* c2W  = (const float*)d_in[10];
    const float* c2as = (const float*)d_in[11];
    const float* c2ad = (const float*)d_in[12];
    const float* c2We = (const float*)d_in[13];
    const float* c2ae = (const float*)d_in[14];
    const float* c2b  = (const float*)d_in[15];
    const int*   ei   = (const int*)d_in[16];
    const int*   eli  = (const int*)d_in[17];
    float* out = (float*)d_out;

    float* w    = (float*)d_ws;
    float* W1c  = w + OFF_W1C;
    float* b1c  = w + OFF_B1C;
    float* ce   = w + OFF_CE;
    float* H    = w + OFF_H;
    float* Agg  = w + OFF_AGG;
    float* Asrc = w + OFF_ASRC;
    float* Adst = w + OFF_ADST;
    int*   rowp = (int*)(w + OFF_ROW);
    int2*  pack = (int2*)(w + OFF_PACK);
    int*   cm   = (int*)(w + OFF_CM);
    int*   om   = (int*)(w + OFF_OM);
    int*   bkb  = (int*)(w + OFF_BKB);
    int2*  tmp  = (int2*)(w + OFF_H);   // aliases H: dead until GEMM-1 (stream-ordered)

    // ---- CSR build (4 dispatches; structure shared by both layers) ----
    blkhist_prep_kernel<<<NBLK, 256, 0, stream>>>(ei, cm, Wa, ba, c1W,
                                                  c1We, c1ae, c2We, c2ae,
                                                  W1c, b1c, ce);
    bucket_scan_kernel<<<NBKT, 256, 0, stream>>>(cm, om, bkb);
    partition_kernel<<<NBLK, 256, 0, stream>>>(ei, ea, om, tmp);
    place_rowptr_kernel<<<NBKT, 256, 0, stream>>>(tmp, bkb, rowp, pack);

    // ---- layer 1: H1 = x @ W1c + b1c ; agg1 = softmax-agg(H1) + c1b, relu ----
    gemm_attn_kernel<<<1024, 256, 0, stream>>>(x, W1c, b1c, 1,
                                               c1as, c1ad, H, Asrc, Adst);
    aggregate_csr_kernel<<<12500, 256, 0, stream>>>(rowp, pack, Asrc, Adst,
                                                    ce + 0, H, Agg, c1b, 1);

    // ---- layer 2: H2 = agg1 @ c2W ; agg2 = softmax-agg(H2) ----
    gemm_attn_kernel<<<1024, 256, 0, stream>>>(Agg, c2W, nullptr, 0,
                                               c2as, c2ad, H, Asrc, Adst);
    aggregate_csr_kernel<<<12500, 256, 0, stream>>>(rowp, pack, Asrc, Adst,
                                                    ce + 1, H, Agg, nullptr, 0);

    // ---- classifier (adds c2b to both operands) ----
    classify_kernel<<<(N_LABEL * 16 + 255) / 256, 256, 0, stream>>>(eli, Agg, c2b, out);
}